// Round 2
// baseline (355.226 us; speedup 1.0000x reference)
//
#include <hip/hip_runtime.h>

#define N_NODES 100000
#define E_EDGES 1600000
// D = HID = 128, H = 4, HD = 32

typedef unsigned short u16;
typedef unsigned int   u32;
typedef float f32x4  __attribute__((ext_vector_type(4)));
typedef short bf16x8 __attribute__((ext_vector_type(8)));

#define NBUK 98            // buckets of 1024 nodes: bucket = tgt >> 10
#define BCAP 20480         // fixed bucket capacity (mean 16384, +32 sigma)

__device__ __forceinline__ u16 f2b(float f) {
  u32 b = __float_as_uint(f);
  return (u16)((b + 0x7FFFu + ((b >> 16) & 1u)) >> 16);
}
__device__ __forceinline__ float blo(u32 u) { return __uint_as_float(u << 16); }
__device__ __forceinline__ float bhi(u32 u) { return __uint_as_float(u & 0xFFFF0000u); }

template<int CTRL>
__device__ __forceinline__ float dpp_add(float d) {
  int x = __builtin_amdgcn_update_dpp(0, __float_as_int(d), CTRL, 0xf, 0xf, true);
  return d + __int_as_float(x);
}
// Reduce across an 8-lane group: xor1, xor2 (quad_perm), then half-row mirror.
__device__ __forceinline__ float reduce8(float d) {
  d = dpp_add<0xB1>(d);    // quad_perm [1,0,3,2]
  d = dpp_add<0x4E>(d);    // quad_perm [2,3,0,1]
  d = dpp_add<0x141>(d);   // row_half_mirror
  return d;
}

// ---------------------------------------------------------------------------
// setup: init bucket cursors to fixed window bases AND transpose+convert W.
// ---------------------------------------------------------------------------
__global__ __launch_bounds__(256) void setup(
    const float* __restrict__ Wq, const float* __restrict__ Wk,
    const float* __restrict__ Wv, const float* __restrict__ Wo,
    u16* __restrict__ Wt, u32* __restrict__ bcur)
{
  int tid = blockIdx.x * 256 + threadIdx.x;
  if (tid < NBUK) bcur[tid] = (u32)tid * BCAP;
  int idx = tid - NBUK;
  if (idx >= 0 && idx < 65536) {
    int mat = idx >> 14;
    int rem = idx & 16383;
    int n = rem >> 7, k = rem & 127;
    const float* W = (mat == 0) ? Wq : (mat == 1) ? Wk : (mat == 2) ? Wv : Wo;
    Wt[idx] = f2b(W[k * 128 + n]);
  }
}

// ---------------------------------------------------------------------------
// Fused QKV: stage A tile once, loop over Wq/Wk/Wv.
// Q -> Qb[node][128] bf16.  K,V -> KVi[node]: elem group g = c>>2 occupies
// u16 slots [8g..8g+7] = {K elems 4g..4g+3, V elems 4g..4g+3}.
// ---------------------------------------------------------------------------
__global__ __launch_bounds__(256) void gemm_qkv(
    const float* __restrict__ A, const u16* __restrict__ Wt,
    const float* __restrict__ bq, const float* __restrict__ bk,
    const float* __restrict__ bv,
    u16* __restrict__ Qb, u16* __restrict__ KVi16, int M)
{
  __shared__ u16 Alds[64][136];
  __shared__ u16 Blds[128][136];
  const int t = threadIdx.x;
  const int row0 = blockIdx.x * 64;

#pragma unroll
  for (int i = 0; i < 8; ++i) {
    int f = t + i * 256;
    int r = f >> 5, c4 = f & 31;
    int gr = row0 + r; if (gr >= M) gr = M - 1;
    float4 v = ((const float4*)(A + (size_t)gr * 128))[c4];
    u16* dst = &Alds[r][c4 * 4];
    dst[0] = f2b(v.x); dst[1] = f2b(v.y); dst[2] = f2b(v.z); dst[3] = f2b(v.w);
  }

  const int lane = t & 63;
  const int mrow = lane & 15;
  const int q    = lane >> 4;
  const int m0   = (t >> 6) * 16;

  for (int m = 0; m < 3; ++m) {
    __syncthreads();
#pragma unroll
    for (int i = 0; i < 8; ++i) {
      int f = t + i * 256;
      int r = f >> 4, c8 = f & 15;
      uint4 v = ((const uint4*)(Wt + (size_t)m * 16384 + (size_t)r * 128))[c8];
      *(uint4*)&Blds[r][c8 * 8] = v;
    }
    __syncthreads();

    f32x4 acc[8];
#pragma unroll
    for (int c = 0; c < 8; ++c) acc[c] = (f32x4){0.f, 0.f, 0.f, 0.f};
#pragma unroll
    for (int kk = 0; kk < 4; ++kk) {
      const int kb = kk * 32 + q * 8;
      bf16x8 a = *(const bf16x8*)&Alds[m0 + mrow][kb];
#pragma unroll
      for (int c = 0; c < 8; ++c) {
        bf16x8 b = *(const bf16x8*)&Blds[c * 16 + mrow][kb];
        acc[c] = __builtin_amdgcn_mfma_f32_16x16x32_bf16(a, b, acc[c], 0, 0, 0);
      }
    }

    const float* bias = (m == 0) ? bq : (m == 1) ? bk : bv;
#pragma unroll
    for (int c = 0; c < 8; ++c) {
      int gcol = c * 16 + mrow;
      float bvv = bias[gcol];
#pragma unroll
      for (int r = 0; r < 4; ++r) {
        int grow = row0 + m0 + q * 4 + r;
        if (grow < M) {
          u16 val = f2b(acc[c][r] + bvv);
          if (m == 0) {
            Qb[(size_t)grow * 128 + gcol] = val;
          } else {
            int slot = ((gcol >> 2) << 3) + ((m == 2) ? 4 : 0) + (gcol & 3);
            KVi16[(size_t)grow * 256 + slot] = val;
          }
        }
      }
    }
  }
}

// ---------------------------------------------------------------------------
// Final: out(Mx128,f32) = A(bf16, Mx128) @ Wo + bo
// ---------------------------------------------------------------------------
__global__ __launch_bounds__(256) void gemm_out(
    const u16* __restrict__ A, const u16* __restrict__ Wt,
    const float* __restrict__ bias, float* __restrict__ Cout, int M)
{
  __shared__ u16 Alds[64][136];
  __shared__ u16 Blds[128][136];
  const int t = threadIdx.x;
  const int row0 = blockIdx.x * 64;

#pragma unroll
  for (int i = 0; i < 4; ++i) {
    int f = t + i * 256;
    int r = f >> 4, c8 = f & 15;
    int gr = row0 + r; if (gr >= M) gr = M - 1;
    uint4 v = ((const uint4*)(A + (size_t)gr * 128))[c8];
    *(uint4*)&Alds[r][c8 * 8] = v;
  }
#pragma unroll
  for (int i = 0; i < 8; ++i) {
    int f = t + i * 256;
    int r = f >> 4, c8 = f & 15;
    uint4 v = ((const uint4*)(Wt + (size_t)r * 128))[c8];
    *(uint4*)&Blds[r][c8 * 8] = v;
  }
  __syncthreads();

  const int lane = t & 63;
  const int mrow = lane & 15;
  const int q    = lane >> 4;
  const int m0   = (t >> 6) * 16;

  f32x4 acc[8];
#pragma unroll
  for (int c = 0; c < 8; ++c) acc[c] = (f32x4){0.f, 0.f, 0.f, 0.f};
#pragma unroll
  for (int kk = 0; kk < 4; ++kk) {
    const int kb = kk * 32 + q * 8;
    bf16x8 a = *(const bf16x8*)&Alds[m0 + mrow][kb];
#pragma unroll
    for (int c = 0; c < 8; ++c) {
      bf16x8 b = *(const bf16x8*)&Blds[c * 16 + mrow][kb];
      acc[c] = __builtin_amdgcn_mfma_f32_16x16x32_bf16(a, b, acc[c], 0, 0, 0);
    }
  }

#pragma unroll
  for (int c = 0; c < 8; ++c) {
    int gcol = c * 16 + mrow;
    float bv = bias[gcol];
#pragma unroll
    for (int r = 0; r < 4; ++r) {
      int grow = row0 + m0 + q * 4 + r;
      if (grow < M) Cout[(size_t)grow * 128 + gcol] = acc[c][r] + bv;
    }
  }
}

// ---------------------------------------------------------------------------
// pass1: bin 4096 edges/block by bucket via LDS counting sort; claim one
// contiguous run per bucket (single atomicAdd on bcur, windows pre-based at
// b*BCAP) and write staged (tgt,payload) pairs in coalesced runs.
// payload = (src<<15) | ew_q15.
// ---------------------------------------------------------------------------
__global__ __launch_bounds__(256) void pass1_bin(
    const int* __restrict__ ei, const float* __restrict__ ew,
    u32* __restrict__ bcur, uint2* __restrict__ stag)
{
  __shared__ u32 s_px[4096];
  __shared__ u32 s_py[4096];
  __shared__ u32 s_gp[4096];
  __shared__ u32 s_hist[NBUK];
  __shared__ u32 s_excl[NBUK];
  __shared__ u32 s_gbase[NBUK];
  __shared__ int s_scan[128];
  const int t = threadIdx.x;
  const int base = blockIdx.x * 4096;
  const int nv = min(4096, E_EDGES - base);

  if (t < NBUK) s_hist[t] = 0;
  __syncthreads();

  u32 tg[16], py[16];
#pragma unroll
  for (int i = 0; i < 16; ++i) {
    int li = t + i * 256;
    bool valid = li < nv;
    int e = base + (valid ? li : 0);
    tg[i] = (u32)ei[E_EDGES + e];
    u32 src = (u32)ei[e];
    u32 ewq = (u32)(ew[e] * 32768.0f);
    py[i] = (src << 15) | ewq;
    if (valid) atomicAdd(&s_hist[tg[i] >> 10], 1u);
    else tg[i] = 0xFFFFFFFFu;
  }
  __syncthreads();

  // scan 98 counts (128-lane ladder; all 256 threads hit the syncs)
  {
    int v = (t < NBUK) ? (int)s_hist[t] : 0;
    if (t < 128) s_scan[t] = v;
    __syncthreads();
    for (int d = 1; d < 128; d <<= 1) {
      int x = (t >= d && t < 128) ? s_scan[t - d] : 0;
      __syncthreads();
      if (t < 128) s_scan[t] += x;
      __syncthreads();
    }
    if (t < NBUK) {
      s_excl[t] = (u32)(s_scan[t] - v);
      s_gbase[t] = (v > 0) ? atomicAdd(&bcur[t], (u32)v) : 0u;
    }
  }
  __syncthreads();
  if (t < NBUK) s_hist[t] = s_excl[t];   // reuse as LDS cursor
  __syncthreads();

#pragma unroll
  for (int i = 0; i < 16; ++i) {
    if (tg[i] != 0xFFFFFFFFu) {
      u32 bk = tg[i] >> 10;
      u32 lp = atomicAdd(&s_hist[bk], 1u);
      s_px[lp] = tg[i];
      s_py[lp] = py[i];
      s_gp[lp] = s_gbase[bk] + (lp - s_excl[bk]);
    }
  }
  __syncthreads();
  for (int s = t; s < nv; s += 256)
    stag[s_gp[s]] = make_uint2(s_px[s], s_py[s]);
}

// ---------------------------------------------------------------------------
// pass2: one block per bucket. LDS per-node histogram + scan -> nodeinfo
// {start,deg}; then scatter staged entries via LDS cursors into the bucket's
// csr window (random writes confined to ~80 KB -> L2-resident).
// ---------------------------------------------------------------------------
__global__ __launch_bounds__(1024) void pass2_scatter(
    const u32* __restrict__ bcur, const uint2* __restrict__ stag,
    int2* __restrict__ nodeinfo, u32* __restrict__ csr)
{
  __shared__ int s_hist[1024];
  __shared__ int s_scan[1024];
  const int t = threadIdx.x;
  const int b = blockIdx.x;
  const int sb = b * BCAP;
  const int cnt = (int)bcur[b] - sb;
  const int node_base = b << 10;

  s_hist[t] = 0;
  __syncthreads();
  for (int i = t; i < cnt; i += 1024)
    atomicAdd(&s_hist[stag[sb + i].x & 1023], 1);
  __syncthreads();

  int v = s_hist[t];
  s_scan[t] = v;
  __syncthreads();
  for (int d = 1; d < 1024; d <<= 1) {
    int x = (t >= d) ? s_scan[t - d] : 0;
    __syncthreads();
    s_scan[t] += x;
    __syncthreads();
  }
  int excl = s_scan[t] - v;
  int node = node_base + t;
  if (node < N_NODES) nodeinfo[node] = make_int2(sb + excl, v);
  __syncthreads();
  s_hist[t] = sb + excl;   // absolute cursor
  __syncthreads();
  for (int i = t; i < cnt; i += 1024) {
    uint2 pr = stag[sb + i];
    int pos = atomicAdd(&s_hist[pr.x & 1023], 1);
    csr[pos] = pr.y;
  }
}

// ---------------------------------------------------------------------------
// Fused per-node gather, 2 edges per wave (lanes 0-31 even edges, 32-63 odd).
// Software-pipelined: stage = 2 pairs (4 edges); KV loads for stage s+1 and
// csr loads for stage s+2 issue before stage s's compute, so csr latency is
// off the critical path and one KV stage is always in flight per wave.
// Math is identical to the round-0 baseline (unpack + f32 FMA dot).
// Within a half: 8 lanes/head, lane owns 4 elems; one uint4 = K-quad+V-quad.
// ---------------------------------------------------------------------------
__global__ __launch_bounds__(256) void gather_fused(
    const int2* __restrict__ nodeinfo, const u32* __restrict__ csr,
    u32* __restrict__ Qb32, const u32* __restrict__ KVi,
    const float* __restrict__ We, const float* __restrict__ be)
{
  int node = blockIdx.x * 4 + (threadIdx.x >> 6);
  int l    = threadIdx.x & 63;
  int half = l >> 5;
  int hl   = l & 31;
  int h    = hl >> 3;

  const float scale = 0.17677669529663687f;   // 1/sqrt(32)
  const float eiq   = 1.0f / 32768.0f;
  uint2 qp = *(const uint2*)(Qb32 + (size_t)node * 64 + hl * 2);
  float qa = blo(qp.x) * scale, qb = bhi(qp.x) * scale;
  float qc = blo(qp.y) * scale, qd = bhi(qp.y) * scale;
  float weq = We[h] * eiq, bE = be[h];
  const u32 laneKV = (u32)hl * 16;

  int2 ni = nodeinfo[node];
  int s0 = ni.x, L = ni.y;
  int npair = L >> 1;
  const u32* cp = csr + s0 + half;
  const char* KVc = (const char*)KVi;

  float a0 = 0.f, a1 = 0.f, a2 = 0.f, a3 = 0.f, sum = 0.f;

  auto LDKV = [&](u32 c) -> uint4 {
    return *(const uint4*)(KVc + (((c >> 15) << 9) + laneKV));
  };
  auto COMP = [&](u32 c, uint4 kv) {
    float d = qa * blo(kv.x) + qb * bhi(kv.x) + qc * blo(kv.y) + qd * bhi(kv.y);
    d = reduce8(d);
    float p = __expf(d + (float)(c & 32767u) * weq + bE);
    sum += p;
    a0 += p * blo(kv.z);
    a1 += p * bhi(kv.z);
    a2 += p * blo(kv.w);
    a3 += p * bhi(kv.w);
  };

  const int nstage = npair >> 1;   // stages of 2 pairs (4 edges)
  u32 cA0 = 0, cA1 = 0, cB0 = 0, cB1 = 0;
  uint4 kA0, kA1;
  if (nstage >= 1) {
    cA0 = cp[0]; cA1 = cp[2];
    kA0 = LDKV(cA0); kA1 = LDKV(cA1);
  }
  if (nstage >= 2) { cB0 = cp[4]; cB1 = cp[6]; }
  for (int s = 0; s + 2 <= nstage; ++s) {
    uint4 kB0 = LDKV(cB0);
    uint4 kB1 = LDKV(cB1);
    u32 cN0 = cB0, cN1 = cB1;
    if (s + 3 <= nstage) { cN0 = cp[4 * s + 8]; cN1 = cp[4 * s + 10]; }
    COMP(cA0, kA0);
    COMP(cA1, kA1);
    cA0 = cB0; cA1 = cB1; kA0 = kB0; kA1 = kB1;
    cB0 = cN0; cB1 = cN1;
  }
  if (nstage >= 1) {
    COMP(cA0, kA0);
    COMP(cA1, kA1);
  }
  // remainder pair (npair odd)
  for (int i = nstage * 2; i < npair; ++i) {
    u32 c = cp[2 * i];
    uint4 kv = LDKV(c);
    COMP(c, kv);
  }
  // odd final edge: both halves load it, half 1 contributes 0
  if (L & 1) {
    u32 c = csr[s0 + L - 1];
    uint4 kv = LDKV(c);
    float d = qa * blo(kv.x) + qb * bhi(kv.x) + qc * blo(kv.y) + qd * bhi(kv.y);
    d = reduce8(d);
    float p = __expf(d + (float)(c & 32767u) * weq + bE);
    p = half ? 0.f : p;
    sum += p;
    a0 += p * blo(kv.z);
    a1 += p * bhi(kv.z);
    a2 += p * blo(kv.w);
    a3 += p * bhi(kv.w);
  }

  sum += __shfl_xor(sum, 32, 64);
  a0  += __shfl_xor(a0, 32, 64);
  a1  += __shfl_xor(a1, 32, 64);
  a2  += __shfl_xor(a2, 32, 64);
  a3  += __shfl_xor(a3, 32, 64);

  float inv = 1.f / (sum + 1e-8f);
  if (half == 0) {
    uint2 w;
    w.x = (u32)f2b(a0 * inv) | ((u32)f2b(a1 * inv) << 16);
    w.y = (u32)f2b(a2 * inv) | ((u32)f2b(a3 * inv) << 16);
    *(uint2*)(Qb32 + (size_t)node * 64 + hl * 2) = w;
  }
}

// ---------------------------------------------------------------------------
extern "C" void kernel_launch(void* const* d_in, const int* in_sizes, int n_in,
                              void* d_out, int out_size, void* d_ws, size_t ws_size,
                              hipStream_t stream) {
  const float* nf = (const float*)d_in[0];
  const int*   ei = (const int*)  d_in[1];
  const float* ew = (const float*)d_in[2];
  const float* Wq = (const float*)d_in[3];
  const float* bq = (const float*)d_in[4];
  const float* Wk = (const float*)d_in[5];
  const float* bk = (const float*)d_in[6];
  const float* Wv = (const float*)d_in[7];
  const float* bv = (const float*)d_in[8];
  const float* Wo = (const float*)d_in[9];
  const float* bo = (const float*)d_in[10];
  const float* We = (const float*)d_in[11];
  const float* be = (const float*)d_in[12];
  float* out = (float*)d_out;

  char* ws = (char*)d_ws;
  u16*  Wt  = (u16*)ws;                                 // 128 KB
  u16*  Qb  = (u16*)(ws + 131072);                      // 25.6 MB
  u16*  KVi16 = Qb + (size_t)N_NODES * 128;             // 51.2 MB
  char* p   = (char*)(KVi16 + (size_t)N_NODES * 256);
  uint2* stag = (uint2*)p;              p += (size_t)NBUK * BCAP * 8;  // 16.1 MB
  u32*  csr = (u32*)p;                  p += (size_t)NBUK * BCAP * 4;  // 8.0 MB
  int2* nodeinfo = (int2*)p;            p += (size_t)N_NODES * 8;      // 0.8 MB
  u32*  bcur = (u32*)p;                 p += 512;

  const int echunks = (E_EDGES + 4095) / 4096;   // 391

  setup<<<(NBUK + 65536 + 255) / 256, 256, 0, stream>>>(Wq, Wk, Wv, Wo, Wt, bcur);

  const int mblocks = (N_NODES + 63) / 64;
  gemm_qkv<<<mblocks, 256, 0, stream>>>(nf, Wt, bq, bk, bv, Qb, KVi16, N_NODES);

  pass1_bin<<<echunks, 256, 0, stream>>>(ei, ew, bcur, stag);
  pass2_scatter<<<NBUK, 1024, 0, stream>>>(bcur, stag, nodeinfo, csr);

  gather_fused<<<N_NODES / 4, 256, 0, stream>>>(nodeinfo, csr,
      (u32*)Qb, (const u32*)KVi16, We, be);

  gemm_out<<<mblocks, 256, 0, stream>>>(Qb, Wt + 49152, bo, out, N_NODES);
}

// Round 3
// 327.000 us; speedup vs baseline: 1.0863x; 1.0863x over previous
//
#include <hip/hip_runtime.h>

#define N_NODES 100000
#define E_EDGES 1600000
// D = HID = 128, H = 4, HD = 32

typedef unsigned short u16;
typedef unsigned int   u32;
typedef unsigned char  u8;
typedef float f32x4  __attribute__((ext_vector_type(4)));
typedef short bf16x8 __attribute__((ext_vector_type(8)));

#define NBUK 98            // buckets of 1024 nodes: bucket = tgt >> 10
#define BCAP 20480         // fixed bucket capacity (mean 16384, +32 sigma)

__device__ __forceinline__ u16 f2b(float f) {
  u32 b = __float_as_uint(f);
  return (u16)((b + 0x7FFFu + ((b >> 16) & 1u)) >> 16);
}
__device__ __forceinline__ float blo(u32 u) { return __uint_as_float(u << 16); }
__device__ __forceinline__ float bhi(u32 u) { return __uint_as_float(u & 0xFFFF0000u); }

// f32 -> OCP e4m3fn, round-to-nearest-even. |f| must be < 448 (holds: |K|<2).
// Trick: y = |f| * 2^-120 puts the e4m3 exponent in the f32 exponent field
// (bits 26:23) and the e4m3 mantissa at bits 22:20; RNE-round at bit 20.
__device__ __forceinline__ u8 f2e4m3(float f) {
  u32 b = __float_as_uint(f);
  u32 s = (b >> 24) & 0x80u;
  float y = __uint_as_float(b & 0x7fffffffu) * 0x1p-120f;
  u32 u = __float_as_uint(y);
  u += 0x7FFFFu + ((u >> 20) & 1u);
  return (u8)(s | ((u >> 20) & 0x7fu));
}

// fallback single-byte e4m3fn -> f32 (bits above 7 of x are ignored)
__device__ __forceinline__ float e4m3_1(u32 x) {
  u32 y = ((x & 0x80u) << 24) | ((x & 0x7fu) << 20);
  return __uint_as_float(y) * 0x1p120f;
}

// decode 4 packed e4m3fn bytes -> 4 floats
__device__ __forceinline__ void dec4(u32 kq, float& k0, float& k1, float& k2, float& k3) {
#if __has_builtin(__builtin_amdgcn_cvt_pk_f32_fp8)
  auto lo = __builtin_amdgcn_cvt_pk_f32_fp8((int)kq, false);   // bytes 0,1
  auto hi = __builtin_amdgcn_cvt_pk_f32_fp8((int)kq, true);    // bytes 2,3
  k0 = lo[0]; k1 = lo[1]; k2 = hi[0]; k3 = hi[1];
#else
  k0 = e4m3_1(kq); k1 = e4m3_1(kq >> 8); k2 = e4m3_1(kq >> 16); k3 = e4m3_1(kq >> 24);
#endif
}

template<int CTRL>
__device__ __forceinline__ float dpp_add(float d) {
  int x = __builtin_amdgcn_update_dpp(0, __float_as_int(d), CTRL, 0xf, 0xf, true);
  return d + __int_as_float(x);
}
// Reduce across an 8-lane group: xor1, xor2 (quad_perm), then half-row mirror.
__device__ __forceinline__ float reduce8(float d) {
  d = dpp_add<0xB1>(d);    // quad_perm [1,0,3,2]
  d = dpp_add<0x4E>(d);    // quad_perm [2,3,0,1]
  d = dpp_add<0x141>(d);   // row_half_mirror
  return d;
}

// ---------------------------------------------------------------------------
// setup: init bucket cursors to fixed window bases AND transpose+convert W.
// ---------------------------------------------------------------------------
__global__ __launch_bounds__(256) void setup(
    const float* __restrict__ Wq, const float* __restrict__ Wk,
    const float* __restrict__ Wv, const float* __restrict__ Wo,
    u16* __restrict__ Wt, u32* __restrict__ bcur)
{
  int tid = blockIdx.x * 256 + threadIdx.x;
  if (tid < NBUK) bcur[tid] = (u32)tid * BCAP;
  int idx = tid - NBUK;
  if (idx >= 0 && idx < 65536) {
    int mat = idx >> 14;
    int rem = idx & 16383;
    int n = rem >> 7, k = rem & 127;
    const float* W = (mat == 0) ? Wq : (mat == 1) ? Wk : (mat == 2) ? Wv : Wo;
    Wt[idx] = f2b(W[k * 128 + n]);
  }
}

// ---------------------------------------------------------------------------
// Fused QKV: stage A tile once, loop over Wq/Wk/Wv.
// Q -> Qb[node][128] bf16.
// K -> Kf8[node][128] fp8 e4m3 (one 128B cache line per row).
// V -> Vb16[node][128] bf16 row-major (256B per row).
// ---------------------------------------------------------------------------
__global__ __launch_bounds__(256) void gemm_qkv(
    const float* __restrict__ A, const u16* __restrict__ Wt,
    const float* __restrict__ bq, const float* __restrict__ bk,
    const float* __restrict__ bv,
    u16* __restrict__ Qb, u8* __restrict__ Kf8, u16* __restrict__ Vb16, int M)
{
  __shared__ u16 Alds[64][136];
  __shared__ u16 Blds[128][136];
  const int t = threadIdx.x;
  const int row0 = blockIdx.x * 64;

#pragma unroll
  for (int i = 0; i < 8; ++i) {
    int f = t + i * 256;
    int r = f >> 5, c4 = f & 31;
    int gr = row0 + r; if (gr >= M) gr = M - 1;
    float4 v = ((const float4*)(A + (size_t)gr * 128))[c4];
    u16* dst = &Alds[r][c4 * 4];
    dst[0] = f2b(v.x); dst[1] = f2b(v.y); dst[2] = f2b(v.z); dst[3] = f2b(v.w);
  }

  const int lane = t & 63;
  const int mrow = lane & 15;
  const int q    = lane >> 4;
  const int m0   = (t >> 6) * 16;

  for (int m = 0; m < 3; ++m) {
    __syncthreads();
#pragma unroll
    for (int i = 0; i < 8; ++i) {
      int f = t + i * 256;
      int r = f >> 4, c8 = f & 15;
      uint4 v = ((const uint4*)(Wt + (size_t)m * 16384 + (size_t)r * 128))[c8];
      *(uint4*)&Blds[r][c8 * 8] = v;
    }
    __syncthreads();

    f32x4 acc[8];
#pragma unroll
    for (int c = 0; c < 8; ++c) acc[c] = (f32x4){0.f, 0.f, 0.f, 0.f};
#pragma unroll
    for (int kk = 0; kk < 4; ++kk) {
      const int kb = kk * 32 + q * 8;
      bf16x8 a = *(const bf16x8*)&Alds[m0 + mrow][kb];
#pragma unroll
      for (int c = 0; c < 8; ++c) {
        bf16x8 b = *(const bf16x8*)&Blds[c * 16 + mrow][kb];
        acc[c] = __builtin_amdgcn_mfma_f32_16x16x32_bf16(a, b, acc[c], 0, 0, 0);
      }
    }

    const float* bias = (m == 0) ? bq : (m == 1) ? bk : bv;
#pragma unroll
    for (int c = 0; c < 8; ++c) {
      int gcol = c * 16 + mrow;
      float bvv = bias[gcol];
#pragma unroll
      for (int r = 0; r < 4; ++r) {
        int grow = row0 + m0 + q * 4 + r;
        if (grow < M) {
          float outv = acc[c][r] + bvv;
          if (m == 0) {
            Qb[(size_t)grow * 128 + gcol] = f2b(outv);
          } else if (m == 1) {
            Kf8[(size_t)grow * 128 + gcol] = f2e4m3(outv);
          } else {
            Vb16[(size_t)grow * 128 + gcol] = f2b(outv);
          }
        }
      }
    }
  }
}

// ---------------------------------------------------------------------------
// Final: out(Mx128,f32) = A(bf16, Mx128) @ Wo + bo
// ---------------------------------------------------------------------------
__global__ __launch_bounds__(256) void gemm_out(
    const u16* __restrict__ A, const u16* __restrict__ Wt,
    const float* __restrict__ bias, float* __restrict__ Cout, int M)
{
  __shared__ u16 Alds[64][136];
  __shared__ u16 Blds[128][136];
  const int t = threadIdx.x;
  const int row0 = blockIdx.x * 64;

#pragma unroll
  for (int i = 0; i < 4; ++i) {
    int f = t + i * 256;
    int r = f >> 4, c8 = f & 15;
    int gr = row0 + r; if (gr >= M) gr = M - 1;
    uint4 v = ((const uint4*)(A + (size_t)gr * 128))[c8];
    *(uint4*)&Alds[r][c8 * 8] = v;
  }
#pragma unroll
  for (int i = 0; i < 8; ++i) {
    int f = t + i * 256;
    int r = f >> 4, c8 = f & 15;
    uint4 v = ((const uint4*)(Wt + (size_t)r * 128))[c8];
    *(uint4*)&Blds[r][c8 * 8] = v;
  }
  __syncthreads();

  const int lane = t & 63;
  const int mrow = lane & 15;
  const int q    = lane >> 4;
  const int m0   = (t >> 6) * 16;

  f32x4 acc[8];
#pragma unroll
  for (int c = 0; c < 8; ++c) acc[c] = (f32x4){0.f, 0.f, 0.f, 0.f};
#pragma unroll
  for (int kk = 0; kk < 4; ++kk) {
    const int kb = kk * 32 + q * 8;
    bf16x8 a = *(const bf16x8*)&Alds[m0 + mrow][kb];
#pragma unroll
    for (int c = 0; c < 8; ++c) {
      bf16x8 b = *(const bf16x8*)&Blds[c * 16 + mrow][kb];
      acc[c] = __builtin_amdgcn_mfma_f32_16x16x32_bf16(a, b, acc[c], 0, 0, 0);
    }
  }

#pragma unroll
  for (int c = 0; c < 8; ++c) {
    int gcol = c * 16 + mrow;
    float bv = bias[gcol];
#pragma unroll
    for (int r = 0; r < 4; ++r) {
      int grow = row0 + m0 + q * 4 + r;
      if (grow < M) Cout[(size_t)grow * 128 + gcol] = acc[c][r] + bv;
    }
  }
}

// ---------------------------------------------------------------------------
// pass1: bin 4096 edges/block by bucket via LDS counting sort; claim one
// contiguous run per bucket (single atomicAdd on bcur, windows pre-based at
// b*BCAP) and write staged (tgt,payload) pairs in coalesced runs.
// payload = (src<<15) | ew_q15.
// ---------------------------------------------------------------------------
__global__ __launch_bounds__(256) void pass1_bin(
    const int* __restrict__ ei, const float* __restrict__ ew,
    u32* __restrict__ bcur, uint2* __restrict__ stag)
{
  __shared__ u32 s_px[4096];
  __shared__ u32 s_py[4096];
  __shared__ u32 s_gp[4096];
  __shared__ u32 s_hist[NBUK];
  __shared__ u32 s_excl[NBUK];
  __shared__ u32 s_gbase[NBUK];
  __shared__ int s_scan[128];
  const int t = threadIdx.x;
  const int base = blockIdx.x * 4096;
  const int nv = min(4096, E_EDGES - base);

  if (t < NBUK) s_hist[t] = 0;
  __syncthreads();

  u32 tg[16], py[16];
#pragma unroll
  for (int i = 0; i < 16; ++i) {
    int li = t + i * 256;
    bool valid = li < nv;
    int e = base + (valid ? li : 0);
    tg[i] = (u32)ei[E_EDGES + e];
    u32 src = (u32)ei[e];
    u32 ewq = (u32)(ew[e] * 32768.0f);
    py[i] = (src << 15) | ewq;
    if (valid) atomicAdd(&s_hist[tg[i] >> 10], 1u);
    else tg[i] = 0xFFFFFFFFu;
  }
  __syncthreads();

  // scan 98 counts (128-lane ladder; all 256 threads hit the syncs)
  {
    int v = (t < NBUK) ? (int)s_hist[t] : 0;
    if (t < 128) s_scan[t] = v;
    __syncthreads();
    for (int d = 1; d < 128; d <<= 1) {
      int x = (t >= d && t < 128) ? s_scan[t - d] : 0;
      __syncthreads();
      if (t < 128) s_scan[t] += x;
      __syncthreads();
    }
    if (t < NBUK) {
      s_excl[t] = (u32)(s_scan[t] - v);
      s_gbase[t] = (v > 0) ? atomicAdd(&bcur[t], (u32)v) : 0u;
    }
  }
  __syncthreads();
  if (t < NBUK) s_hist[t] = s_excl[t];   // reuse as LDS cursor
  __syncthreads();

#pragma unroll
  for (int i = 0; i < 16; ++i) {
    if (tg[i] != 0xFFFFFFFFu) {
      u32 bk = tg[i] >> 10;
      u32 lp = atomicAdd(&s_hist[bk], 1u);
      s_px[lp] = tg[i];
      s_py[lp] = py[i];
      s_gp[lp] = s_gbase[bk] + (lp - s_excl[bk]);
    }
  }
  __syncthreads();
  for (int s = t; s < nv; s += 256)
    stag[s_gp[s]] = make_uint2(s_px[s], s_py[s]);
}

// ---------------------------------------------------------------------------
// pass2: one block per bucket. LDS per-node histogram + scan -> nodeinfo
// {start,deg}; then scatter staged entries via LDS cursors into the bucket's
// csr window (random writes confined to ~80 KB -> L2-resident).
// ---------------------------------------------------------------------------
__global__ __launch_bounds__(1024) void pass2_scatter(
    const u32* __restrict__ bcur, const uint2* __restrict__ stag,
    int2* __restrict__ nodeinfo, u32* __restrict__ csr)
{
  __shared__ int s_hist[1024];
  __shared__ int s_scan[1024];
  const int t = threadIdx.x;
  const int b = blockIdx.x;
  const int sb = b * BCAP;
  const int cnt = (int)bcur[b] - sb;
  const int node_base = b << 10;

  s_hist[t] = 0;
  __syncthreads();
  for (int i = t; i < cnt; i += 1024)
    atomicAdd(&s_hist[stag[sb + i].x & 1023], 1);
  __syncthreads();

  int v = s_hist[t];
  s_scan[t] = v;
  __syncthreads();
  for (int d = 1; d < 1024; d <<= 1) {
    int x = (t >= d) ? s_scan[t - d] : 0;
    __syncthreads();
    s_scan[t] += x;
    __syncthreads();
  }
  int excl = s_scan[t] - v;
  int node = node_base + t;
  if (node < N_NODES) nodeinfo[node] = make_int2(sb + excl, v);
  __syncthreads();
  s_hist[t] = sb + excl;   // absolute cursor
  __syncthreads();
  for (int i = t; i < cnt; i += 1024) {
    uint2 pr = stag[sb + i];
    int pos = atomicAdd(&s_hist[pr.x & 1023], 1);
    csr[pos] = pr.y;
  }
}

// ---------------------------------------------------------------------------
// Fused per-node gather, 2 edges per wave (lanes 0-31 even edges, 32-63 odd),
// 4-pair unroll -> 8 edges in flight per wave.
// Within a half: 8 lanes/head, lane owns elems [4hl..4hl+3]:
//   K: one dword of fp8 at Krow + 4*hl   (row = 128 B = 1 cache line)
//   V: one dwordx2 of bf16 at Vrow + 8*hl (row = 256 B = 2 lines)
// Per edge: 384 B vs 512 B for the old interleaved bf16 KV (-25%).
// ---------------------------------------------------------------------------
__global__ __launch_bounds__(256) void gather_fused(
    const int2* __restrict__ nodeinfo, const u32* __restrict__ csr,
    u32* __restrict__ Qb32, const u8* __restrict__ Kf8,
    const u32* __restrict__ Vb,
    const float* __restrict__ We, const float* __restrict__ be)
{
  int node = blockIdx.x * 4 + (threadIdx.x >> 6);
  int l    = threadIdx.x & 63;
  int half = l >> 5;
  int hl   = l & 31;
  int h    = hl >> 3;

  const float scale = 0.17677669529663687f;   // 1/sqrt(32)
  const float eiq   = 1.0f / 32768.0f;
  uint2 qp = *(const uint2*)(Qb32 + (size_t)node * 64 + hl * 2);
  float qa = blo(qp.x) * scale, qb = bhi(qp.x) * scale;
  float qc = blo(qp.y) * scale, qd = bhi(qp.y) * scale;
  float weq = We[h] * eiq, bE = be[h];
  const u32 laneK = (u32)hl * 4;
  const u32 laneV = (u32)hl * 8;

  int2 ni = nodeinfo[node];
  int s0 = ni.x, L = ni.y;
  int npair = L >> 1;
  const u32* cp = csr + s0 + half;
  const char* Kc = (const char*)Kf8;
  const char* Vc = (const char*)Vb;

  float a0 = 0.f, a1 = 0.f, a2 = 0.f, a3 = 0.f, sum = 0.f;

  auto LDK = [&](u32 c) -> u32 {
    return *(const u32*)(Kc + (((c >> 15) << 7) + laneK));
  };
  auto LDV = [&](u32 c) -> uint2 {
    return *(const uint2*)(Vc + (((c >> 15) << 8) + laneV));
  };
  auto COMP = [&](u32 c, u32 kq, uint2 vv) {
    float k0, k1, k2, k3;
    dec4(kq, k0, k1, k2, k3);
    float d = qa * k0 + qb * k1 + qc * k2 + qd * k3;
    d = reduce8(d);
    float p = __expf(d + (float)(c & 32767u) * weq + bE);
    sum += p;
    a0 += p * blo(vv.x);
    a1 += p * bhi(vv.x);
    a2 += p * blo(vv.y);
    a3 += p * bhi(vv.y);
  };

  int i = 0;
  for (; i + 4 <= npair; i += 4) {
    u32 c0 = cp[2 * i];
    u32 c1 = cp[2 * i + 2];
    u32 c2 = cp[2 * i + 4];
    u32 c3 = cp[2 * i + 6];
    u32 k0 = LDK(c0), k1 = LDK(c1), k2 = LDK(c2), k3 = LDK(c3);
    uint2 v0 = LDV(c0), v1 = LDV(c1), v2 = LDV(c2), v3 = LDV(c3);
    COMP(c0, k0, v0);
    COMP(c1, k1, v1);
    COMP(c2, k2, v2);
    COMP(c3, k3, v3);
  }
  for (; i < npair; ++i) {
    u32 c = cp[2 * i];
    u32 kq = LDK(c);
    uint2 vv = LDV(c);
    COMP(c, kq, vv);
  }
  // odd final edge: both halves load it, half 1 contributes 0
  if (L & 1) {
    u32 c = csr[s0 + L - 1];
    u32 kq = LDK(c);
    uint2 vv = LDV(c);
    float k0, k1, k2, k3;
    dec4(kq, k0, k1, k2, k3);
    float d = qa * k0 + qb * k1 + qc * k2 + qd * k3;
    d = reduce8(d);
    float p = __expf(d + (float)(c & 32767u) * weq + bE);
    p = half ? 0.f : p;
    sum += p;
    a0 += p * blo(vv.x);
    a1 += p * bhi(vv.x);
    a2 += p * blo(vv.y);
    a3 += p * bhi(vv.y);
  }

  sum += __shfl_xor(sum, 32, 64);
  a0  += __shfl_xor(a0, 32, 64);
  a1  += __shfl_xor(a1, 32, 64);
  a2  += __shfl_xor(a2, 32, 64);
  a3  += __shfl_xor(a3, 32, 64);

  float inv = 1.f / (sum + 1e-8f);
  if (half == 0) {
    uint2 w;
    w.x = (u32)f2b(a0 * inv) | ((u32)f2b(a1 * inv) << 16);
    w.y = (u32)f2b(a2 * inv) | ((u32)f2b(a3 * inv) << 16);
    *(uint2*)(Qb32 + (size_t)node * 64 + hl * 2) = w;
  }
}

// ---------------------------------------------------------------------------
extern "C" void kernel_launch(void* const* d_in, const int* in_sizes, int n_in,
                              void* d_out, int out_size, void* d_ws, size_t ws_size,
                              hipStream_t stream) {
  const float* nf = (const float*)d_in[0];
  const int*   ei = (const int*)  d_in[1];
  const float* ew = (const float*)d_in[2];
  const float* Wq = (const float*)d_in[3];
  const float* bq = (const float*)d_in[4];
  const float* Wk = (const float*)d_in[5];
  const float* bk = (const float*)d_in[6];
  const float* Wv = (const float*)d_in[7];
  const float* bv = (const float*)d_in[8];
  const float* Wo = (const float*)d_in[9];
  const float* bo = (const float*)d_in[10];
  const float* We = (const float*)d_in[11];
  const float* be = (const float*)d_in[12];
  float* out = (float*)d_out;

  char* ws = (char*)d_ws;
  u16*  Wt  = (u16*)ws;                                 // 128 KB
  u16*  Qb  = (u16*)(ws + 131072);                      // 25.6 MB
  u8*   Kf8 = (u8*)(Qb + (size_t)N_NODES * 128);        // 12.8 MB
  u16*  Vb16 = (u16*)(Kf8 + (size_t)N_NODES * 128);     // 25.6 MB
  char* p   = (char*)(Vb16 + (size_t)N_NODES * 128);
  uint2* stag = (uint2*)p;              p += (size_t)NBUK * BCAP * 8;  // 16.1 MB
  u32*  csr = (u32*)p;                  p += (size_t)NBUK * BCAP * 4;  // 8.0 MB
  int2* nodeinfo = (int2*)p;            p += (size_t)N_NODES * 8;      // 0.8 MB
  u32*  bcur = (u32*)p;                 p += 512;

  const int echunks = (E_EDGES + 4095) / 4096;   // 391

  setup<<<(NBUK + 65536 + 255) / 256, 256, 0, stream>>>(Wq, Wk, Wv, Wo, Wt, bcur);

  const int mblocks = (N_NODES + 63) / 64;
  gemm_qkv<<<mblocks, 256, 0, stream>>>(nf, Wt, bq, bk, bv, Qb, Kf8, Vb16, N_NODES);

  pass1_bin<<<echunks, 256, 0, stream>>>(ei, ew, bcur, stag);
  pass2_scatter<<<NBUK, 1024, 0, stream>>>(bcur, stag, nodeinfo, csr);

  gather_fused<<<N_NODES / 4, 256, 0, stream>>>(nodeinfo, csr,
      (u32*)Qb, Kf8, (const u32*)Vb16, We, be);

  gemm_out<<<mblocks, 256, 0, stream>>>(Qb, Wt + 49152, bo, out, N_NODES);
}

// Round 4
// 321.615 us; speedup vs baseline: 1.1045x; 1.0167x over previous
//
#include <hip/hip_runtime.h>

#define N_NODES 100000
#define E_EDGES 1600000
// D = HID = 128, H = 4, HD = 32

typedef unsigned short u16;
typedef unsigned int   u32;
typedef unsigned char  u8;
typedef float f32x4  __attribute__((ext_vector_type(4)));
typedef short bf16x8 __attribute__((ext_vector_type(8)));

#define NBUK 98            // buckets of 1024 nodes: bucket = tgt >> 10
#define BCAP 20480         // fixed bucket capacity (mean 16384, +32 sigma)

__device__ __forceinline__ u16 f2b(float f) {
  u32 b = __float_as_uint(f);
  return (u16)((b + 0x7FFFu + ((b >> 16) & 1u)) >> 16);
}
__device__ __forceinline__ float blo(u32 u) { return __uint_as_float(u << 16); }
__device__ __forceinline__ float bhi(u32 u) { return __uint_as_float(u & 0xFFFF0000u); }

// f32 -> OCP e4m3fn, round-to-nearest-even. |f| must be < 448 (holds: |K|<2).
__device__ __forceinline__ u8 f2e4m3(float f) {
  u32 b = __float_as_uint(f);
  u32 s = (b >> 24) & 0x80u;
  float y = __uint_as_float(b & 0x7fffffffu) * 0x1p-120f;
  u32 u = __float_as_uint(y);
  u += 0x7FFFFu + ((u >> 20) & 1u);
  return (u8)(s | ((u >> 20) & 0x7fu));
}

// fallback single-byte e4m3fn -> f32
__device__ __forceinline__ float e4m3_1(u32 x) {
  u32 y = ((x & 0x80u) << 24) | ((x & 0x7fu) << 20);
  return __uint_as_float(y) * 0x1p120f;
}

// decode 4 packed e4m3fn bytes -> 4 floats
__device__ __forceinline__ void dec4(u32 kq, float& k0, float& k1, float& k2, float& k3) {
#if __has_builtin(__builtin_amdgcn_cvt_pk_f32_fp8)
  auto lo = __builtin_amdgcn_cvt_pk_f32_fp8((int)kq, false);   // bytes 0,1
  auto hi = __builtin_amdgcn_cvt_pk_f32_fp8((int)kq, true);    // bytes 2,3
  k0 = lo[0]; k1 = lo[1]; k2 = hi[0]; k3 = hi[1];
#else
  k0 = e4m3_1(kq); k1 = e4m3_1(kq >> 8); k2 = e4m3_1(kq >> 16); k3 = e4m3_1(kq >> 24);
#endif
}

template<int CTRL>
__device__ __forceinline__ float dpp_add(float d) {
  int x = __builtin_amdgcn_update_dpp(0, __float_as_int(d), CTRL, 0xf, 0xf, true);
  return d + __int_as_float(x);
}
// Reduce across an 8-lane group: xor1, xor2 (quad_perm), then half-row mirror.
__device__ __forceinline__ float reduce8(float d) {
  d = dpp_add<0xB1>(d);    // quad_perm [1,0,3,2]
  d = dpp_add<0x4E>(d);    // quad_perm [2,3,0,1]
  d = dpp_add<0x141>(d);   // row_half_mirror
  return d;
}

// ---------------------------------------------------------------------------
// setup: init bucket cursors to fixed window bases AND transpose+convert W.
// ---------------------------------------------------------------------------
__global__ __launch_bounds__(256) void setup(
    const float* __restrict__ Wq, const float* __restrict__ Wk,
    const float* __restrict__ Wv, const float* __restrict__ Wo,
    u16* __restrict__ Wt, u32* __restrict__ bcur)
{
  int tid = blockIdx.x * 256 + threadIdx.x;
  if (tid < NBUK) bcur[tid] = (u32)tid * BCAP;
  int idx = tid - NBUK;
  if (idx >= 0 && idx < 65536) {
    int mat = idx >> 14;
    int rem = idx & 16383;
    int n = rem >> 7, k = rem & 127;
    const float* W = (mat == 0) ? Wq : (mat == 1) ? Wk : (mat == 2) ? Wv : Wo;
    Wt[idx] = f2b(W[k * 128 + n]);
  }
}

// ---------------------------------------------------------------------------
// Fused QKV: stage A tile once, loop over Wq/Wk/Wv.
// Q -> Qb[node][128] bf16.
// K -> Kf8[node][128] fp8 e4m3 (one 128B cache line per row).
// V -> Vb16[node][128] bf16 row-major (256B per row).
// ---------------------------------------------------------------------------
__global__ __launch_bounds__(256) void gemm_qkv(
    const float* __restrict__ A, const u16* __restrict__ Wt,
    const float* __restrict__ bq, const float* __restrict__ bk,
    const float* __restrict__ bv,
    u16* __restrict__ Qb, u8* __restrict__ Kf8, u16* __restrict__ Vb16, int M)
{
  __shared__ u16 Alds[64][136];
  __shared__ u16 Blds[128][136];
  const int t = threadIdx.x;
  const int row0 = blockIdx.x * 64;

#pragma unroll
  for (int i = 0; i < 8; ++i) {
    int f = t + i * 256;
    int r = f >> 5, c4 = f & 31;
    int gr = row0 + r; if (gr >= M) gr = M - 1;
    float4 v = ((const float4*)(A + (size_t)gr * 128))[c4];
    u32* dst = (u32*)&Alds[r][c4 * 4];
    dst[0] = (u32)f2b(v.x) | ((u32)f2b(v.y) << 16);
    dst[1] = (u32)f2b(v.z) | ((u32)f2b(v.w) << 16);
  }

  const int lane = t & 63;
  const int mrow = lane & 15;
  const int q    = lane >> 4;
  const int m0   = (t >> 6) * 16;

  for (int m = 0; m < 3; ++m) {
    __syncthreads();
#pragma unroll
    for (int i = 0; i < 8; ++i) {
      int f = t + i * 256;
      int r = f >> 4, c8 = f & 15;
      uint4 v = ((const uint4*)(Wt + (size_t)m * 16384 + (size_t)r * 128))[c8];
      *(uint4*)&Blds[r][c8 * 8] = v;
    }
    __syncthreads();

    f32x4 acc[8];
#pragma unroll
    for (int c = 0; c < 8; ++c) acc[c] = (f32x4){0.f, 0.f, 0.f, 0.f};
#pragma unroll
    for (int kk = 0; kk < 4; ++kk) {
      const int kb = kk * 32 + q * 8;
      bf16x8 a = *(const bf16x8*)&Alds[m0 + mrow][kb];
#pragma unroll
      for (int c = 0; c < 8; ++c) {
        bf16x8 b = *(const bf16x8*)&Blds[c * 16 + mrow][kb];
        acc[c] = __builtin_amdgcn_mfma_f32_16x16x32_bf16(a, b, acc[c], 0, 0, 0);
      }
    }

    const float* bias = (m == 0) ? bq : (m == 1) ? bk : bv;
#pragma unroll
    for (int c = 0; c < 8; ++c) {
      int gcol = c * 16 + mrow;
      float bvv = bias[gcol];
#pragma unroll
      for (int r = 0; r < 4; ++r) {
        int grow = row0 + m0 + q * 4 + r;
        if (grow < M) {
          float outv = acc[c][r] + bvv;
          if (m == 0) {
            Qb[(size_t)grow * 128 + gcol] = f2b(outv);
          } else if (m == 1) {
            Kf8[(size_t)grow * 128 + gcol] = f2e4m3(outv);
          } else {
            Vb16[(size_t)grow * 128 + gcol] = f2b(outv);
          }
        }
      }
    }
  }
}

// ---------------------------------------------------------------------------
// Final: out(Mx128,f32) = A(bf16, Mx128) @ Wo + bo
// ---------------------------------------------------------------------------
__global__ __launch_bounds__(256) void gemm_out(
    const u16* __restrict__ A, const u16* __restrict__ Wt,
    const float* __restrict__ bias, float* __restrict__ Cout, int M)
{
  __shared__ u16 Alds[64][136];
  __shared__ u16 Blds[128][136];
  const int t = threadIdx.x;
  const int row0 = blockIdx.x * 64;

#pragma unroll
  for (int i = 0; i < 4; ++i) {
    int f = t + i * 256;
    int r = f >> 4, c8 = f & 15;
    int gr = row0 + r; if (gr >= M) gr = M - 1;
    uint4 v = ((const uint4*)(A + (size_t)gr * 128))[c8];
    *(uint4*)&Alds[r][c8 * 8] = v;
  }
#pragma unroll
  for (int i = 0; i < 8; ++i) {
    int f = t + i * 256;
    int r = f >> 4, c8 = f & 15;
    uint4 v = ((const uint4*)(Wt + (size_t)r * 128))[c8];
    *(uint4*)&Blds[r][c8 * 8] = v;
  }
  __syncthreads();

  const int lane = t & 63;
  const int mrow = lane & 15;
  const int q    = lane >> 4;
  const int m0   = (t >> 6) * 16;

  f32x4 acc[8];
#pragma unroll
  for (int c = 0; c < 8; ++c) acc[c] = (f32x4){0.f, 0.f, 0.f, 0.f};
#pragma unroll
  for (int kk = 0; kk < 4; ++kk) {
    const int kb = kk * 32 + q * 8;
    bf16x8 a = *(const bf16x8*)&Alds[m0 + mrow][kb];
#pragma unroll
    for (int c = 0; c < 8; ++c) {
      bf16x8 b = *(const bf16x8*)&Blds[c * 16 + mrow][kb];
      acc[c] = __builtin_amdgcn_mfma_f32_16x16x32_bf16(a, b, acc[c], 0, 0, 0);
    }
  }

#pragma unroll
  for (int c = 0; c < 8; ++c) {
    int gcol = c * 16 + mrow;
    float bv = bias[gcol];
#pragma unroll
    for (int r = 0; r < 4; ++r) {
      int grow = row0 + m0 + q * 4 + r;
      if (grow < M) Cout[(size_t)grow * 128 + gcol] = acc[c][r] + bv;
    }
  }
}

// ---------------------------------------------------------------------------
// pass1: bin 4096 edges/block by bucket via LDS counting sort; claim one
// contiguous run per bucket and write staged (tgt,payload) pairs coalesced.
// payload = (src<<15) | ew_q15.
// Loads vectorized int4/float4 (in-block edge order permuted — harmless);
// scan over 98 buckets via 2-wave shfl scan (2 syncs instead of 14).
// ---------------------------------------------------------------------------
__global__ __launch_bounds__(256) void pass1_bin(
    const int* __restrict__ ei, const float* __restrict__ ew,
    u32* __restrict__ bcur, uint2* __restrict__ stag)
{
  __shared__ u32 s_px[4096];
  __shared__ u32 s_py[4096];
  __shared__ u32 s_gp[4096];
  __shared__ u32 s_hist[NBUK];
  __shared__ u32 s_excl[NBUK];
  __shared__ u32 s_gbase[NBUK];
  __shared__ u32 s_wsum[4];
  const int t = threadIdx.x;
  const int base = blockIdx.x * 4096;
  const int nv = min(4096, E_EDGES - base);   // nv % 4 == 0 always

  if (t < NBUK) s_hist[t] = 0;
  __syncthreads();

  u32 tg[16], py[16];
  const int4*   src4 = (const int4*)(ei + base);
  const int4*   tgt4 = (const int4*)(ei + E_EDGES + base);
  const float4* ewv4 = (const float4*)(ew + base);
#pragma unroll
  for (int j = 0; j < 4; ++j) {
    int q4 = t + j * 256;                 // int4 index
    bool valid = (q4 * 4) < nv;           // whole-vector validity (nv%4==0)
    int qq = valid ? q4 : 0;
    int4   sv = src4[qq];
    int4   tv = tgt4[qq];
    float4 wv = ewv4[qq];
    u32* TG = &tg[j * 4];
    u32* PY = &py[j * 4];
    TG[0] = (u32)tv.x; TG[1] = (u32)tv.y; TG[2] = (u32)tv.z; TG[3] = (u32)tv.w;
    PY[0] = ((u32)sv.x << 15) | (u32)(wv.x * 32768.0f);
    PY[1] = ((u32)sv.y << 15) | (u32)(wv.y * 32768.0f);
    PY[2] = ((u32)sv.z << 15) | (u32)(wv.z * 32768.0f);
    PY[3] = ((u32)sv.w << 15) | (u32)(wv.w * 32768.0f);
    if (valid) {
      atomicAdd(&s_hist[TG[0] >> 10], 1u);
      atomicAdd(&s_hist[TG[1] >> 10], 1u);
      atomicAdd(&s_hist[TG[2] >> 10], 1u);
      atomicAdd(&s_hist[TG[3] >> 10], 1u);
    } else {
      TG[0] = TG[1] = TG[2] = TG[3] = 0xFFFFFFFFu;
    }
  }
  __syncthreads();

  // scan 98 bucket counts: 64-lane shfl scans + cross-wave fixup (2 syncs)
  {
    int v = (t < NBUK) ? (int)s_hist[t] : 0;
    int x = v;
#pragma unroll
    for (int d = 1; d < 64; d <<= 1) {
      int y = __shfl_up(x, d, 64);
      if ((t & 63) >= d) x += y;
    }
    if ((t & 63) == 63 && t < 128) s_wsum[t >> 6] = (u32)x;
    __syncthreads();
    if (t < NBUK) {
      int incl = x + ((t >= 64) ? (int)s_wsum[0] : 0);
      s_excl[t] = (u32)(incl - v);
      s_gbase[t] = (v > 0) ? atomicAdd(&bcur[t], (u32)v) : 0u;
    }
  }
  __syncthreads();
  if (t < NBUK) s_hist[t] = s_excl[t];   // reuse as LDS cursor
  __syncthreads();

#pragma unroll
  for (int i = 0; i < 16; ++i) {
    if (tg[i] != 0xFFFFFFFFu) {
      u32 bk = tg[i] >> 10;
      u32 lp = atomicAdd(&s_hist[bk], 1u);
      s_px[lp] = tg[i];
      s_py[lp] = py[i];
      s_gp[lp] = s_gbase[bk] + (lp - s_excl[bk]);
    }
  }
  __syncthreads();
  for (int s = t; s < nv; s += 256)
    stag[s_gp[s]] = make_uint2(s_px[s], s_py[s]);
}

// ---------------------------------------------------------------------------
// pass2: one block per bucket. LDS per-node histogram + scan -> nodeinfo
// {start,deg}; then scatter staged entries via LDS cursors into the bucket's
// csr window. Global loads 4-way batched (dependent-latency amortized);
// 1024-entry scan via shfl wave scans + 16-wavesum scan (3 syncs, not 20).
// ---------------------------------------------------------------------------
__global__ __launch_bounds__(1024) void pass2_scatter(
    const u32* __restrict__ bcur, const uint2* __restrict__ stag,
    int2* __restrict__ nodeinfo, u32* __restrict__ csr)
{
  __shared__ int s_hist[1024];
  __shared__ int s_wsum[16];
  const int t = threadIdx.x;
  const int b = blockIdx.x;
  const int sb = b * BCAP;
  const int cnt = (int)bcur[b] - sb;
  const int node_base = b << 10;

  s_hist[t] = 0;
  __syncthreads();

  // histogram, 4-batched
  int i = t;
  for (; i + 3072 < cnt; i += 4096) {
    uint2 e0 = stag[sb + i];
    uint2 e1 = stag[sb + i + 1024];
    uint2 e2 = stag[sb + i + 2048];
    uint2 e3 = stag[sb + i + 3072];
    atomicAdd(&s_hist[e0.x & 1023], 1);
    atomicAdd(&s_hist[e1.x & 1023], 1);
    atomicAdd(&s_hist[e2.x & 1023], 1);
    atomicAdd(&s_hist[e3.x & 1023], 1);
  }
  for (; i < cnt; i += 1024)
    atomicAdd(&s_hist[stag[sb + i].x & 1023], 1);
  __syncthreads();

  // hierarchical inclusive scan of 1024 counts
  int v = s_hist[t];
  int x = v;
#pragma unroll
  for (int d = 1; d < 64; d <<= 1) {
    int y = __shfl_up(x, d, 64);
    if ((t & 63) >= d) x += y;
  }
  if ((t & 63) == 63) s_wsum[t >> 6] = x;
  __syncthreads();
  if (t < 64) {
    int w = (t < 16) ? s_wsum[t] : 0;
#pragma unroll
    for (int d = 1; d < 16; d <<= 1) {
      int y = __shfl_up(w, d, 64);
      if (t >= d) w += y;
    }
    if (t < 16) s_wsum[t] = w;   // inclusive wave-sum prefix
  }
  __syncthreads();
  int wbase = (t >= 64) ? s_wsum[(t >> 6) - 1] : 0;
  int excl = x + wbase - v;
  int node = node_base + t;
  if (node < N_NODES) nodeinfo[node] = make_int2(sb + excl, v);
  __syncthreads();
  s_hist[t] = sb + excl;   // absolute cursor
  __syncthreads();

  // scatter, 4-batched
  i = t;
  for (; i + 3072 < cnt; i += 4096) {
    uint2 e0 = stag[sb + i];
    uint2 e1 = stag[sb + i + 1024];
    uint2 e2 = stag[sb + i + 2048];
    uint2 e3 = stag[sb + i + 3072];
    int p0 = atomicAdd(&s_hist[e0.x & 1023], 1);
    int p1 = atomicAdd(&s_hist[e1.x & 1023], 1);
    int p2 = atomicAdd(&s_hist[e2.x & 1023], 1);
    int p3 = atomicAdd(&s_hist[e3.x & 1023], 1);
    csr[p0] = e0.y;
    csr[p1] = e1.y;
    csr[p2] = e2.y;
    csr[p3] = e3.y;
  }
  for (; i < cnt; i += 1024) {
    uint2 pr = stag[sb + i];
    int pos = atomicAdd(&s_hist[pr.x & 1023], 1);
    csr[pos] = pr.y;
  }
}

// ---------------------------------------------------------------------------
// Fused per-node gather, 2 edges per wave (lanes 0-31 even edges, 32-63 odd),
// 4-pair unroll -> 8 edges in flight per wave.
// Within a half: 8 lanes/head, lane owns elems [4hl..4hl+3]:
//   K: one dword of fp8 at Krow + 4*hl   (row = 128 B = 1 cache line)
//   V: one dwordx2 of bf16 at Vrow + 8*hl (row = 256 B = 2 lines)
// ---------------------------------------------------------------------------
__global__ __launch_bounds__(256) void gather_fused(
    const int2* __restrict__ nodeinfo, const u32* __restrict__ csr,
    u32* __restrict__ Qb32, const u8* __restrict__ Kf8,
    const u32* __restrict__ Vb,
    const float* __restrict__ We, const float* __restrict__ be)
{
  int node = blockIdx.x * 4 + (threadIdx.x >> 6);
  int l    = threadIdx.x & 63;
  int half = l >> 5;
  int hl   = l & 31;
  int h    = hl >> 3;

  const float scale = 0.17677669529663687f;   // 1/sqrt(32)
  const float eiq   = 1.0f / 32768.0f;
  uint2 qp = *(const uint2*)(Qb32 + (size_t)node * 64 + hl * 2);
  float qa = blo(qp.x) * scale, qb = bhi(qp.x) * scale;
  float qc = blo(qp.y) * scale, qd = bhi(qp.y) * scale;
  float weq = We[h] * eiq, bE = be[h];
  const u32 laneK = (u32)hl * 4;
  const u32 laneV = (u32)hl * 8;

  int2 ni = nodeinfo[node];
  int s0 = ni.x, L = ni.y;
  int npair = L >> 1;
  const u32* cp = csr + s0 + half;
  const char* Kc = (const char*)Kf8;
  const char* Vc = (const char*)Vb;

  float a0 = 0.f, a1 = 0.f, a2 = 0.f, a3 = 0.f, sum = 0.f;

  auto LDK = [&](u32 c) -> u32 {
    return *(const u32*)(Kc + (((c >> 15) << 7) + laneK));
  };
  auto LDV = [&](u32 c) -> uint2 {
    return *(const uint2*)(Vc + (((c >> 15) << 8) + laneV));
  };
  auto COMP = [&](u32 c, u32 kq, uint2 vv) {
    float k0, k1, k2, k3;
    dec4(kq, k0, k1, k2, k3);
    float d = qa * k0 + qb * k1 + qc * k2 + qd * k3;
    d = reduce8(d);
    float p = __expf(d + (float)(c & 32767u) * weq + bE);
    sum += p;
    a0 += p * blo(vv.x);
    a1 += p * bhi(vv.x);
    a2 += p * blo(vv.y);
    a3 += p * bhi(vv.y);
  };

  int i = 0;
  for (; i + 4 <= npair; i += 4) {
    u32 c0 = cp[2 * i];
    u32 c1 = cp[2 * i + 2];
    u32 c2 = cp[2 * i + 4];
    u32 c3 = cp[2 * i + 6];
    u32 k0 = LDK(c0), k1 = LDK(c1), k2 = LDK(c2), k3 = LDK(c3);
    uint2 v0 = LDV(c0), v1 = LDV(c1), v2 = LDV(c2), v3 = LDV(c3);
    COMP(c0, k0, v0);
    COMP(c1, k1, v1);
    COMP(c2, k2, v2);
    COMP(c3, k3, v3);
  }
  for (; i < npair; ++i) {
    u32 c = cp[2 * i];
    u32 kq = LDK(c);
    uint2 vv = LDV(c);
    COMP(c, kq, vv);
  }
  // odd final edge: both halves load it, half 1 contributes 0
  if (L & 1) {
    u32 c = csr[s0 + L - 1];
    u32 kq = LDK(c);
    uint2 vv = LDV(c);
    float k0, k1, k2, k3;
    dec4(kq, k0, k1, k2, k3);
    float d = qa * k0 + qb * k1 + qc * k2 + qd * k3;
    d = reduce8(d);
    float p = __expf(d + (float)(c & 32767u) * weq + bE);
    p = half ? 0.f : p;
    sum += p;
    a0 += p * blo(vv.x);
    a1 += p * bhi(vv.x);
    a2 += p * blo(vv.y);
    a3 += p * bhi(vv.y);
  }

  sum += __shfl_xor(sum, 32, 64);
  a0  += __shfl_xor(a0, 32, 64);
  a1  += __shfl_xor(a1, 32, 64);
  a2  += __shfl_xor(a2, 32, 64);
  a3  += __shfl_xor(a3, 32, 64);

  float inv = 1.f / (sum + 1e-8f);
  if (half == 0) {
    uint2 w;
    w.x = (u32)f2b(a0 * inv) | ((u32)f2b(a1 * inv) << 16);
    w.y = (u32)f2b(a2 * inv) | ((u32)f2b(a3 * inv) << 16);
    *(uint2*)(Qb32 + (size_t)node * 64 + hl * 2) = w;
  }
}

// ---------------------------------------------------------------------------
extern "C" void kernel_launch(void* const* d_in, const int* in_sizes, int n_in,
                              void* d_out, int out_size, void* d_ws, size_t ws_size,
                              hipStream_t stream) {
  const float* nf = (const float*)d_in[0];
  const int*   ei = (const int*)  d_in[1];
  const float* ew = (const float*)d_in[2];
  const float* Wq = (const float*)d_in[3];
  const float* bq = (const float*)d_in[4];
  const float* Wk = (const float*)d_in[5];
  const float* bk = (const float*)d_in[6];
  const float* Wv = (const float*)d_in[7];
  const float* bv = (const float*)d_in[8];
  const float* Wo = (const float*)d_in[9];
  const float* bo = (const float*)d_in[10];
  const float* We = (const float*)d_in[11];
  const float* be = (const float*)d_in[12];
  float* out = (float*)d_out;

  char* ws = (char*)d_ws;
  u16*  Wt  = (u16*)ws;                                 // 128 KB
  u16*  Qb  = (u16*)(ws + 131072);                      // 25.6 MB
  u8*   Kf8 = (u8*)(Qb + (size_t)N_NODES * 128);        // 12.8 MB
  u16*  Vb16 = (u16*)(Kf8 + (size_t)N_NODES * 128);     // 25.6 MB
  char* p   = (char*)(Vb16 + (size_t)N_NODES * 128);
  uint2* stag = (uint2*)p;              p += (size_t)NBUK * BCAP * 8;  // 16.1 MB
  u32*  csr = (u32*)p;                  p += (size_t)NBUK * BCAP * 4;  // 8.0 MB
  int2* nodeinfo = (int2*)p;            p += (size_t)N_NODES * 8;      // 0.8 MB
  u32*  bcur = (u32*)p;                 p += 512;

  const int echunks = (E_EDGES + 4095) / 4096;   // 391

  setup<<<(NBUK + 65536 + 255) / 256, 256, 0, stream>>>(Wq, Wk, Wv, Wo, Wt, bcur);

  const int mblocks = (N_NODES + 63) / 64;
  gemm_qkv<<<mblocks, 256, 0, stream>>>(nf, Wt, bq, bk, bv, Qb, Kf8, Vb16, N_NODES);

  pass1_bin<<<echunks, 256, 0, stream>>>(ei, ew, bcur, stag);
  pass2_scatter<<<NBUK, 1024, 0, stream>>>(bcur, stag, nodeinfo, csr);

  gather_fused<<<N_NODES / 4, 256, 0, stream>>>(nodeinfo, csr,
      (u32*)Qb, Kf8, (const u32*)Vb16, We, be);

  gemm_out<<<mblocks, 256, 0, stream>>>(Qb, Wt + 49152, bo, out, N_NODES);
}

// Round 5
// 275.331 us; speedup vs baseline: 1.2902x; 1.1681x over previous
//
#include <hip/hip_runtime.h>

#define N_NODES 100000
#define E_EDGES 1600000
// D = HID = 128, H = 4, HD = 32

typedef unsigned short u16;
typedef unsigned int   u32;
typedef unsigned char  u8;
typedef float f32x4  __attribute__((ext_vector_type(4)));
typedef short bf16x8 __attribute__((ext_vector_type(8)));

#define NBUK 98            // buckets of 1024 nodes: bucket = tgt >> 10
#define BCAP 20480         // fixed bucket capacity (mean 16384, +32 sigma)
#define MBLOCKS 1563       // ceil(N_NODES/64)
#define ECHUNKS 391        // ceil(E_EDGES/4096)

__device__ __forceinline__ u16 f2b(float f) {
  u32 b = __float_as_uint(f);
  return (u16)((b + 0x7FFFu + ((b >> 16) & 1u)) >> 16);
}
__device__ __forceinline__ float blo(u32 u) { return __uint_as_float(u << 16); }
__device__ __forceinline__ float bhi(u32 u) { return __uint_as_float(u & 0xFFFF0000u); }

// f32 -> OCP e4m3fn, round-to-nearest-even. |f| must be < 448 (holds: |K|<2).
__device__ __forceinline__ u8 f2e4m3(float f) {
  u32 b = __float_as_uint(f);
  u32 s = (b >> 24) & 0x80u;
  float y = __uint_as_float(b & 0x7fffffffu) * 0x1p-120f;
  u32 u = __float_as_uint(y);
  u += 0x7FFFFu + ((u >> 20) & 1u);
  return (u8)(s | ((u >> 20) & 0x7fu));
}

// fallback single-byte e4m3fn -> f32
__device__ __forceinline__ float e4m3_1(u32 x) {
  u32 y = ((x & 0x80u) << 24) | ((x & 0x7fu) << 20);
  return __uint_as_float(y) * 0x1p120f;
}

// decode 4 packed e4m3fn bytes -> 4 floats
__device__ __forceinline__ void dec4(u32 kq, float& k0, float& k1, float& k2, float& k3) {
#if __has_builtin(__builtin_amdgcn_cvt_pk_f32_fp8)
  auto lo = __builtin_amdgcn_cvt_pk_f32_fp8((int)kq, false);   // bytes 0,1
  auto hi = __builtin_amdgcn_cvt_pk_f32_fp8((int)kq, true);    // bytes 2,3
  k0 = lo[0]; k1 = lo[1]; k2 = hi[0]; k3 = hi[1];
#else
  k0 = e4m3_1(kq); k1 = e4m3_1(kq >> 8); k2 = e4m3_1(kq >> 16); k3 = e4m3_1(kq >> 24);
#endif
}

template<int CTRL>
__device__ __forceinline__ float dpp_add(float d) {
  int x = __builtin_amdgcn_update_dpp(0, __float_as_int(d), CTRL, 0xf, 0xf, true);
  return d + __int_as_float(x);
}
// Reduce across an 8-lane group: xor1, xor2 (quad_perm), then half-row mirror.
__device__ __forceinline__ float reduce8(float d) {
  d = dpp_add<0xB1>(d);    // quad_perm [1,0,3,2]
  d = dpp_add<0x4E>(d);    // quad_perm [2,3,0,1]
  d = dpp_add<0x141>(d);   // row_half_mirror
  return d;
}

// ---------------------------------------------------------------------------
// setup: init bucket cursors to fixed window bases AND transpose+convert W.
// ---------------------------------------------------------------------------
__global__ __launch_bounds__(256) void setup(
    const float* __restrict__ Wq, const float* __restrict__ Wk,
    const float* __restrict__ Wv, const float* __restrict__ Wo,
    u16* __restrict__ Wt, u32* __restrict__ bcur)
{
  int tid = blockIdx.x * 256 + threadIdx.x;
  if (tid < NBUK) bcur[tid] = (u32)tid * BCAP;
  int idx = tid - NBUK;
  if (idx >= 0 && idx < 65536) {
    int mat = idx >> 14;
    int rem = idx & 16383;
    int n = rem >> 7, k = rem & 127;
    const float* W = (mat == 0) ? Wq : (mat == 1) ? Wk : (mat == 2) ? Wv : Wo;
    Wt[idx] = f2b(W[k * 128 + n]);
  }
}

// ---------------------------------------------------------------------------
// Fused block-role kernel: blocks [0, MBLOCKS) run the QKV GEMM; blocks
// [MBLOCKS, MBLOCKS+ECHUNKS) run pass1 edge binning. The two are independent
// (both depend only on setup) — fusing overlaps MFMA-bound and memory-bound
// work and removes one launch + one serialization point.
// Manual LDS aliasing: one 52224 B arena, laid out per role.
// ---------------------------------------------------------------------------
__global__ __launch_bounds__(256) void qkv_pass1(
    const float* __restrict__ A, const u16* __restrict__ Wt,
    const float* __restrict__ bq, const float* __restrict__ bk,
    const float* __restrict__ bv,
    u16* __restrict__ Qb, u8* __restrict__ Kf8, u16* __restrict__ Vb16, int M,
    const int* __restrict__ ei, const float* __restrict__ ew,
    u32* __restrict__ bcur, uint2* __restrict__ stag)
{
  __shared__ __align__(16) char smem[52224];
  const int t = threadIdx.x;

  if ((int)blockIdx.x < MBLOCKS) {
    // ---------------- QKV GEMM role ----------------
    typedef u16 row136[136];
    row136* Alds = (row136*)smem;              // 64 x 136 u16 = 17408 B
    row136* Blds = (row136*)(smem + 17408);    // 128 x 136 u16 = 34816 B
    const int row0 = blockIdx.x * 64;

#pragma unroll
    for (int i = 0; i < 8; ++i) {
      int f = t + i * 256;
      int r = f >> 5, c4 = f & 31;
      int gr = row0 + r; if (gr >= M) gr = M - 1;
      float4 v = ((const float4*)(A + (size_t)gr * 128))[c4];
      u32* dst = (u32*)&Alds[r][c4 * 4];
      dst[0] = (u32)f2b(v.x) | ((u32)f2b(v.y) << 16);
      dst[1] = (u32)f2b(v.z) | ((u32)f2b(v.w) << 16);
    }

    const int lane = t & 63;
    const int mrow = lane & 15;
    const int q    = lane >> 4;
    const int m0   = (t >> 6) * 16;

    for (int m = 0; m < 3; ++m) {
      __syncthreads();
#pragma unroll
      for (int i = 0; i < 8; ++i) {
        int f = t + i * 256;
        int r = f >> 4, c8 = f & 15;
        uint4 v = ((const uint4*)(Wt + (size_t)m * 16384 + (size_t)r * 128))[c8];
        *(uint4*)&Blds[r][c8 * 8] = v;
      }
      __syncthreads();

      f32x4 acc[8];
#pragma unroll
      for (int c = 0; c < 8; ++c) acc[c] = (f32x4){0.f, 0.f, 0.f, 0.f};
#pragma unroll
      for (int kk = 0; kk < 4; ++kk) {
        const int kb = kk * 32 + q * 8;
        bf16x8 a = *(const bf16x8*)&Alds[m0 + mrow][kb];
#pragma unroll
        for (int c = 0; c < 8; ++c) {
          bf16x8 b = *(const bf16x8*)&Blds[c * 16 + mrow][kb];
          acc[c] = __builtin_amdgcn_mfma_f32_16x16x32_bf16(a, b, acc[c], 0, 0, 0);
        }
      }

      const float* bias = (m == 0) ? bq : (m == 1) ? bk : bv;
      __syncthreads();   // all waves done reading Blds -> reuse as staging
      if (m == 1) {
        // K: stage e4m3 bytes, then coalesced uint4 stores (8 KB tile)
        u8* Kst = (u8*)Blds;
#pragma unroll
        for (int c = 0; c < 8; ++c) {
          int gcol = c * 16 + mrow;
          float bvv = bias[gcol];
#pragma unroll
          for (int r = 0; r < 4; ++r)
            Kst[(m0 + q * 4 + r) * 128 + gcol] = f2e4m3(acc[c][r] + bvv);
        }
        __syncthreads();
#pragma unroll
        for (int i = 0; i < 2; ++i) {
          int f = t + i * 256;
          int r = f >> 3, c16 = f & 7;
          int grow = row0 + r;
          if (grow < M)
            *(uint4*)(Kf8 + (size_t)grow * 128 + c16 * 16) =
                *(const uint4*)(Kst + r * 128 + c16 * 16);
        }
      } else {
        // Q / V: stage bf16, then coalesced uint4 stores (16 KB tile)
        u16* St = (u16*)Blds;
#pragma unroll
        for (int c = 0; c < 8; ++c) {
          int gcol = c * 16 + mrow;
          float bvv = bias[gcol];
#pragma unroll
          for (int r = 0; r < 4; ++r)
            St[(m0 + q * 4 + r) * 128 + gcol] = f2b(acc[c][r] + bvv);
        }
        __syncthreads();
        u16* dstM = (m == 0) ? Qb : Vb16;
#pragma unroll
        for (int i = 0; i < 4; ++i) {
          int f = t + i * 256;
          int r = f >> 4, c8 = f & 15;
          int grow = row0 + r;
          if (grow < M)
            *(uint4*)(dstM + (size_t)grow * 128 + c8 * 8) =
                *(const uint4*)(St + r * 128 + c8 * 8);
        }
      }
    }
  } else {
    // ---------------- pass1 edge-binning role ----------------
    u32* s_px    = (u32*)smem;               // 4096 u32
    u32* s_py    = (u32*)(smem + 16384);     // 4096 u32
    u32* s_gp    = (u32*)(smem + 32768);     // 4096 u32
    u32* s_hist  = (u32*)(smem + 49152);     // NBUK
    u32* s_excl  = (u32*)(smem + 49544);     // NBUK
    u32* s_gbase = (u32*)(smem + 49936);     // NBUK
    u32* s_wsum  = (u32*)(smem + 50328);     // 4

    const int base = ((int)blockIdx.x - MBLOCKS) * 4096;
    const int nv = min(4096, E_EDGES - base);   // nv % 4 == 0 always

    if (t < NBUK) s_hist[t] = 0;
    __syncthreads();

    u32 tg[16], py[16];
    const int4*   src4 = (const int4*)(ei + base);
    const int4*   tgt4 = (const int4*)(ei + E_EDGES + base);
    const float4* ewv4 = (const float4*)(ew + base);
#pragma unroll
    for (int j = 0; j < 4; ++j) {
      int q4 = t + j * 256;                 // int4 index
      bool valid = (q4 * 4) < nv;           // whole-vector validity (nv%4==0)
      int qq = valid ? q4 : 0;
      int4   sv = src4[qq];
      int4   tv = tgt4[qq];
      float4 wv = ewv4[qq];
      u32* TG = &tg[j * 4];
      u32* PY = &py[j * 4];
      TG[0] = (u32)tv.x; TG[1] = (u32)tv.y; TG[2] = (u32)tv.z; TG[3] = (u32)tv.w;
      PY[0] = ((u32)sv.x << 15) | (u32)(wv.x * 32768.0f);
      PY[1] = ((u32)sv.y << 15) | (u32)(wv.y * 32768.0f);
      PY[2] = ((u32)sv.z << 15) | (u32)(wv.z * 32768.0f);
      PY[3] = ((u32)sv.w << 15) | (u32)(wv.w * 32768.0f);
      if (valid) {
        atomicAdd(&s_hist[TG[0] >> 10], 1u);
        atomicAdd(&s_hist[TG[1] >> 10], 1u);
        atomicAdd(&s_hist[TG[2] >> 10], 1u);
        atomicAdd(&s_hist[TG[3] >> 10], 1u);
      } else {
        TG[0] = TG[1] = TG[2] = TG[3] = 0xFFFFFFFFu;
      }
    }
    __syncthreads();

    // scan 98 bucket counts: 64-lane shfl scans + cross-wave fixup
    {
      int v = (t < NBUK) ? (int)s_hist[t] : 0;
      int x = v;
#pragma unroll
      for (int d = 1; d < 64; d <<= 1) {
        int y = __shfl_up(x, d, 64);
        if ((t & 63) >= d) x += y;
      }
      if ((t & 63) == 63 && t < 128) s_wsum[t >> 6] = (u32)x;
      __syncthreads();
      if (t < NBUK) {
        int incl = x + ((t >= 64) ? (int)s_wsum[0] : 0);
        s_excl[t] = (u32)(incl - v);
        s_gbase[t] = (v > 0) ? atomicAdd(&bcur[t], (u32)v) : 0u;
      }
    }
    __syncthreads();
    if (t < NBUK) s_hist[t] = s_excl[t];   // reuse as LDS cursor
    __syncthreads();

#pragma unroll
    for (int i = 0; i < 16; ++i) {
      if (tg[i] != 0xFFFFFFFFu) {
        u32 bk = tg[i] >> 10;
        u32 lp = atomicAdd(&s_hist[bk], 1u);
        s_px[lp] = tg[i];
        s_py[lp] = py[i];
        s_gp[lp] = s_gbase[bk] + (lp - s_excl[bk]);
      }
    }
    __syncthreads();
    for (int s = t; s < nv; s += 256)
      stag[s_gp[s]] = make_uint2(s_px[s], s_py[s]);
  }
}

// ---------------------------------------------------------------------------
// Final: out(Mx128,f32) = A(bf16, Mx128) @ Wo + bo
// Epilogue staged through LDS -> coalesced float4 stores.
// ---------------------------------------------------------------------------
__global__ __launch_bounds__(256) void gemm_out(
    const u16* __restrict__ A, const u16* __restrict__ Wt,
    const float* __restrict__ bias, float* __restrict__ Cout, int M)
{
  __shared__ __align__(16) u16 Alds[64][136];
  __shared__ __align__(16) u16 Blds[128][136];
  const int t = threadIdx.x;
  const int row0 = blockIdx.x * 64;

#pragma unroll
  for (int i = 0; i < 4; ++i) {
    int f = t + i * 256;
    int r = f >> 4, c8 = f & 15;
    int gr = row0 + r; if (gr >= M) gr = M - 1;
    uint4 v = ((const uint4*)(A + (size_t)gr * 128))[c8];
    *(uint4*)&Alds[r][c8 * 8] = v;
  }
#pragma unroll
  for (int i = 0; i < 8; ++i) {
    int f = t + i * 256;
    int r = f >> 4, c8 = f & 15;
    uint4 v = ((const uint4*)(Wt + (size_t)r * 128))[c8];
    *(uint4*)&Blds[r][c8 * 8] = v;
  }
  __syncthreads();

  const int lane = t & 63;
  const int mrow = lane & 15;
  const int q    = lane >> 4;
  const int m0   = (t >> 6) * 16;

  f32x4 acc[8];
#pragma unroll
  for (int c = 0; c < 8; ++c) acc[c] = (f32x4){0.f, 0.f, 0.f, 0.f};
#pragma unroll
  for (int kk = 0; kk < 4; ++kk) {
    const int kb = kk * 32 + q * 8;
    bf16x8 a = *(const bf16x8*)&Alds[m0 + mrow][kb];
#pragma unroll
    for (int c = 0; c < 8; ++c) {
      bf16x8 b = *(const bf16x8*)&Blds[c * 16 + mrow][kb];
      acc[c] = __builtin_amdgcn_mfma_f32_16x16x32_bf16(a, b, acc[c], 0, 0, 0);
    }
  }

  // stage f32 tile (64 x 128, padded stride 132) into Blds memory
  __syncthreads();   // all waves done reading Blds
  float* Fst = (float*)&Blds[0][0];
#pragma unroll
  for (int c = 0; c < 8; ++c) {
    int gcol = c * 16 + mrow;
    float bv = bias[gcol];
#pragma unroll
    for (int r = 0; r < 4; ++r)
      Fst[(m0 + q * 4 + r) * 132 + gcol] = acc[c][r] + bv;
  }
  __syncthreads();
#pragma unroll
  for (int i = 0; i < 8; ++i) {
    int f = t + i * 256;
    int r = f >> 5, c4 = f & 31;
    int grow = row0 + r;
    if (grow < M)
      *(float4*)(Cout + (size_t)grow * 128 + c4 * 4) =
          *(const float4*)(Fst + r * 132 + c4 * 4);
  }
}

// ---------------------------------------------------------------------------
// pass2: one block per bucket. Single global read of stag into REGISTERS
// (20-deep unrolled, static-indexed); LDS per-node histogram + shfl scan ->
// nodeinfo {start,deg}; scatter from registers via LDS cursors into the
// bucket's csr window.
// ---------------------------------------------------------------------------
__global__ __launch_bounds__(1024) void pass2_scatter(
    const u32* __restrict__ bcur, const uint2* __restrict__ stag,
    int2* __restrict__ nodeinfo, u32* __restrict__ csr)
{
  __shared__ int s_hist[1024];
  __shared__ int s_wsum[16];
  const int t = threadIdx.x;
  const int b = blockIdx.x;
  const int sb = b * BCAP;
  const int cnt = (int)bcur[b] - sb;
  const int node_base = b << 10;

  s_hist[t] = 0;
  __syncthreads();

  // single pass over stag: payload + node-id into registers, histogram to LDS
  u32 tgr[20], pyr[20];
#pragma unroll
  for (int k = 0; k < 20; ++k) {
    int i = t + k * 1024;
    if (i < cnt) {
      uint2 e = stag[sb + i];
      tgr[k] = e.x & 1023u;
      pyr[k] = e.y;
      atomicAdd(&s_hist[tgr[k]], 1);
    } else {
      tgr[k] = 0xFFFFFFFFu;
      pyr[k] = 0u;
    }
  }
  __syncthreads();

  // hierarchical inclusive scan of 1024 counts
  int v = s_hist[t];
  int x = v;
#pragma unroll
  for (int d = 1; d < 64; d <<= 1) {
    int y = __shfl_up(x, d, 64);
    if ((t & 63) >= d) x += y;
  }
  if ((t & 63) == 63) s_wsum[t >> 6] = x;
  __syncthreads();
  if (t < 64) {
    int w = (t < 16) ? s_wsum[t] : 0;
#pragma unroll
    for (int d = 1; d < 16; d <<= 1) {
      int y = __shfl_up(w, d, 64);
      if (t >= d) w += y;
    }
    if (t < 16) s_wsum[t] = w;   // inclusive wave-sum prefix
  }
  __syncthreads();
  int wbase = (t >= 64) ? s_wsum[(t >> 6) - 1] : 0;
  int excl = x + wbase - v;
  int node = node_base + t;
  if (node < N_NODES) nodeinfo[node] = make_int2(sb + excl, v);
  __syncthreads();
  s_hist[t] = sb + excl;   // absolute cursor
  __syncthreads();

  // scatter from registers
#pragma unroll
  for (int k = 0; k < 20; ++k) {
    if (tgr[k] != 0xFFFFFFFFu) {
      int pos = atomicAdd(&s_hist[tgr[k]], 1);
      csr[pos] = pyr[k];
    }
  }
}

// ---------------------------------------------------------------------------
// Fused per-node gather, 2 edges per wave (lanes 0-31 even edges, 32-63 odd),
// 4-pair unroll -> 8 edges in flight per wave.  [FROZEN since round 3]
// Within a half: 8 lanes/head, lane owns elems [4hl..4hl+3]:
//   K: one dword of fp8 at Krow + 4*hl   (row = 128 B = 1 cache line)
//   V: one dwordx2 of bf16 at Vrow + 8*hl (row = 256 B = 2 lines)
// ---------------------------------------------------------------------------
__global__ __launch_bounds__(256) void gather_fused(
    const int2* __restrict__ nodeinfo, const u32* __restrict__ csr,
    u32* __restrict__ Qb32, const u8* __restrict__ Kf8,
    const u32* __restrict__ Vb,
    const float* __restrict__ We, const float* __restrict__ be)
{
  int node = blockIdx.x * 4 + (threadIdx.x >> 6);
  int l    = threadIdx.x & 63;
  int half = l >> 5;
  int hl   = l & 31;
  int h    = hl >> 3;

  const float scale = 0.17677669529663687f;   // 1/sqrt(32)
  const float eiq   = 1.0f / 32768.0f;
  uint2 qp = *(const uint2*)(Qb32 + (size_t)node * 64 + hl * 2);
  float qa = blo(qp.x) * scale, qb = bhi(qp.x) * scale;
  float qc = blo(qp.y) * scale, qd = bhi(qp.y) * scale;
  float weq = We[h] * eiq, bE = be[h];
  const u32 laneK = (u32)hl * 4;
  const u32 laneV = (u32)hl * 8;

  int2 ni = nodeinfo[node];
  int s0 = ni.x, L = ni.y;
  int npair = L >> 1;
  const u32* cp = csr + s0 + half;
  const char* Kc = (const char*)Kf8;
  const char* Vc = (const char*)Vb;

  float a0 = 0.f, a1 = 0.f, a2 = 0.f, a3 = 0.f, sum = 0.f;

  auto LDK = [&](u32 c) -> u32 {
    return *(const u32*)(Kc + (((c >> 15) << 7) + laneK));
  };
  auto LDV = [&](u32 c) -> uint2 {
    return *(const uint2*)(Vc + (((c >> 15) << 8) + laneV));
  };
  auto COMP = [&](u32 c, u32 kq, uint2 vv) {
    float k0, k1, k2, k3;
    dec4(kq, k0, k1, k2, k3);
    float d = qa * k0 + qb * k1 + qc * k2 + qd * k3;
    d = reduce8(d);
    float p = __expf(d + (float)(c & 32767u) * weq + bE);
    sum += p;
    a0 += p * blo(vv.x);
    a1 += p * bhi(vv.x);
    a2 += p * blo(vv.y);
    a3 += p * bhi(vv.y);
  };

  int i = 0;
  for (; i + 4 <= npair; i += 4) {
    u32 c0 = cp[2 * i];
    u32 c1 = cp[2 * i + 2];
    u32 c2 = cp[2 * i + 4];
    u32 c3 = cp[2 * i + 6];
    u32 k0 = LDK(c0), k1 = LDK(c1), k2 = LDK(c2), k3 = LDK(c3);
    uint2 v0 = LDV(c0), v1 = LDV(c1), v2 = LDV(c2), v3 = LDV(c3);
    COMP(c0, k0, v0);
    COMP(c1, k1, v1);
    COMP(c2, k2, v2);
    COMP(c3, k3, v3);
  }
  for (; i < npair; ++i) {
    u32 c = cp[2 * i];
    u32 kq = LDK(c);
    uint2 vv = LDV(c);
    COMP(c, kq, vv);
  }
  // odd final edge: both halves load it, half 1 contributes 0
  if (L & 1) {
    u32 c = csr[s0 + L - 1];
    u32 kq = LDK(c);
    uint2 vv = LDV(c);
    float k0, k1, k2, k3;
    dec4(kq, k0, k1, k2, k3);
    float d = qa * k0 + qb * k1 + qc * k2 + qd * k3;
    d = reduce8(d);
    float p = __expf(d + (float)(c & 32767u) * weq + bE);
    p = half ? 0.f : p;
    sum += p;
    a0 += p * blo(vv.x);
    a1 += p * bhi(vv.x);
    a2 += p * blo(vv.y);
    a3 += p * bhi(vv.y);
  }

  sum += __shfl_xor(sum, 32, 64);
  a0  += __shfl_xor(a0, 32, 64);
  a1  += __shfl_xor(a1, 32, 64);
  a2  += __shfl_xor(a2, 32, 64);
  a3  += __shfl_xor(a3, 32, 64);

  float inv = 1.f / (sum + 1e-8f);
  if (half == 0) {
    uint2 w;
    w.x = (u32)f2b(a0 * inv) | ((u32)f2b(a1 * inv) << 16);
    w.y = (u32)f2b(a2 * inv) | ((u32)f2b(a3 * inv) << 16);
    *(uint2*)(Qb32 + (size_t)node * 64 + hl * 2) = w;
  }
}

// ---------------------------------------------------------------------------
extern "C" void kernel_launch(void* const* d_in, const int* in_sizes, int n_in,
                              void* d_out, int out_size, void* d_ws, size_t ws_size,
                              hipStream_t stream) {
  const float* nf = (const float*)d_in[0];
  const int*   ei = (const int*)  d_in[1];
  const float* ew = (const float*)d_in[2];
  const float* Wq = (const float*)d_in[3];
  const float* bq = (const float*)d_in[4];
  const float* Wk = (const float*)d_in[5];
  const float* bk = (const float*)d_in[6];
  const float* Wv = (const float*)d_in[7];
  const float* bv = (const float*)d_in[8];
  const float* Wo = (const float*)d_in[9];
  const float* bo = (const float*)d_in[10];
  const float* We = (const float*)d_in[11];
  const float* be = (const float*)d_in[12];
  float* out = (float*)d_out;

  char* ws = (char*)d_ws;
  u16*  Wt  = (u16*)ws;                                 // 128 KB
  u16*  Qb  = (u16*)(ws + 131072);                      // 25.6 MB
  u8*   Kf8 = (u8*)(Qb + (size_t)N_NODES * 128);        // 12.8 MB
  u16*  Vb16 = (u16*)(Kf8 + (size_t)N_NODES * 128);     // 25.6 MB
  char* p   = (char*)(Vb16 + (size_t)N_NODES * 128);
  uint2* stag = (uint2*)p;              p += (size_t)NBUK * BCAP * 8;  // 16.1 MB
  u32*  csr = (u32*)p;                  p += (size_t)NBUK * BCAP * 4;  // 8.0 MB
  int2* nodeinfo = (int2*)p;            p += (size_t)N_NODES * 8;      // 0.8 MB
  u32*  bcur = (u32*)p;                 p += 512;

  setup<<<(NBUK + 65536 + 255) / 256, 256, 0, stream>>>(Wq, Wk, Wv, Wo, Wt, bcur);

  qkv_pass1<<<MBLOCKS + ECHUNKS, 256, 0, stream>>>(
      nf, Wt, bq, bk, bv, Qb, Kf8, Vb16, N_NODES, ei, ew, bcur, stag);

  pass2_scatter<<<NBUK, 1024, 0, stream>>>(bcur, stag, nodeinfo, csr);

  gather_fused<<<N_NODES / 4, 256, 0, stream>>>(nodeinfo, csr,
      (u32*)Qb, Kf8, (const u32*)Vb16, We, be);

  gemm_out<<<MBLOCKS, 256, 0, stream>>>(Qb, Wt + 49152, bo, out, N_NODES);
}